// Round 2
// baseline (728.118 us; speedup 1.0000x reference)
//
#include <hip/hip_runtime.h>
#include <hip/hip_fp16.h>
#include <math.h>

#define N_NODES 100000
#define D_FEAT  128
#define E_EDGES 1600000
#define E2      (E_EDGES + N_NODES)   /* 1,700,000 with self-loops */
#define NEG_SLOPE 0.2f
#define LN_EPS    1e-5f

#define NB   391                      /* buckets of 256 nodes: d >> 8 */
#define TS   8192                     /* edges per tile */
#define NTIL ((E2 + TS - 1) / TS)     /* 208 */

typedef __attribute__((ext_vector_type(8))) short short8;
typedef __attribute__((ext_vector_type(4))) float floatx4;
typedef _Float16 h2 __attribute__((ext_vector_type(2)));   // packed half pair

static __device__ __forceinline__ float fdot2f(h2 a, h2 b, float c) {
#if __has_builtin(__builtin_amdgcn_fdot2)
    return __builtin_amdgcn_fdot2(a, b, c, false);
#else
    return (float)a[0] * (float)b[0] + (float)a[1] * (float)b[1] + c;
#endif
}

static __device__ __forceinline__ h2 shfl_xor_h2(h2 v, int off) {
    int i = __builtin_bit_cast(int, v);
    i = __shfl_xor(i, off);
    return __builtin_bit_cast(h2, i);
}

// ---------------------------------------------------------------------------
// CSR build, zero global atomics:
//  1) tile_count : per-tile LDS hist -> tcnt[tile][bucket]
//  2) col_scan   : per-bucket scan over tiles -> toff, bucket totals bcnt
//  3) bucket_scan: scan bucket totals -> bstart; rowstart[N]=E2
//  4) tile_scatter: deterministic dest = bstart[b]+toff[tile][b]+LDS-rank,
//                   packed pair (src | dst_low<<17) -> pairbuf
//  5) bucketize  : per bucket (256 nodes, 1024 thr) count+scan+scatter
// ---------------------------------------------------------------------------
__global__ __launch_bounds__(1024) void tile_count(const int* __restrict__ edge_dst,
                                                   int* __restrict__ tcnt) {
    __shared__ int h[NB];
    const int t = threadIdx.x;
    if (t < NB) h[t] = 0;
    __syncthreads();
    const int base = blockIdx.x * TS;
#pragma unroll
    for (int j = 0; j < TS / 1024; ++j) {
        int i = base + j * 1024 + t;
        if (i < E2) {
            int d = (i < E_EDGES) ? edge_dst[i] : (i - E_EDGES);
            atomicAdd(&h[d >> 8], 1);
        }
    }
    __syncthreads();
    if (t < NB) tcnt[blockIdx.x * NB + t] = h[t];
}

__global__ __launch_bounds__(256) void col_scan(const int* __restrict__ tcnt,
                                                int* __restrict__ toff,
                                                int* __restrict__ bcnt) {
    __shared__ int s[256];
    const int b = blockIdx.x;
    const int t = threadIdx.x;
    int v = (t < NTIL) ? tcnt[t * NB + b] : 0;
    s[t] = v;
    __syncthreads();
    for (int off = 1; off < 256; off <<= 1) {
        int x = (t >= off) ? s[t - off] : 0;
        __syncthreads();
        s[t] += x;
        __syncthreads();
    }
    if (t < NTIL) toff[t * NB + b] = s[t] - v;   // exclusive
    if (t == 255) bcnt[b] = s[255];
}

__global__ __launch_bounds__(512) void bucket_scan(const int* __restrict__ bcnt,
                                                   int* __restrict__ bstart,
                                                   int* __restrict__ rowstart) {
    __shared__ int s[512];
    const int t = threadIdx.x;
    int v = (t < NB) ? bcnt[t] : 0;
    s[t] = v;
    __syncthreads();
    for (int off = 1; off < 512; off <<= 1) {
        int x = (t >= off) ? s[t - off] : 0;
        __syncthreads();
        s[t] += x;
        __syncthreads();
    }
    if (t <= NB) bstart[t] = s[t] - v;   // t==NB: total == E2
    if (t == 0) rowstart[N_NODES] = E2;
}

__global__ __launch_bounds__(1024) void tile_scatter(const int* __restrict__ edge_src,
                                                     const int* __restrict__ edge_dst,
                                                     const int* __restrict__ bstart,
                                                     const int* __restrict__ toff,
                                                     unsigned* __restrict__ pairbuf) {
    __shared__ int base[NB];
    __shared__ int cur[NB];
    const int t = threadIdx.x;
    if (t < NB) { base[t] = bstart[t] + toff[blockIdx.x * NB + t]; cur[t] = 0; }
    __syncthreads();
    const int tb = blockIdx.x * TS;
#pragma unroll
    for (int j = 0; j < TS / 1024; ++j) {
        int i = tb + j * 1024 + t;
        if (i < E2) {
            int d, sr;
            if (i < E_EDGES) { d = edge_dst[i]; sr = edge_src[i]; }
            else             { d = i - E_EDGES; sr = d; }
            int b = d >> 8;
            int rank = atomicAdd(&cur[b], 1);
            pairbuf[base[b] + rank] = (unsigned)sr | ((unsigned)(d & 255) << 17);
        }
    }
}

__global__ __launch_bounds__(1024) void bucketize(const unsigned* __restrict__ pairbuf,
                                                  const int* __restrict__ bstart,
                                                  int* __restrict__ rowstart,
                                                  int* __restrict__ csr_src) {
    __shared__ int cnt[256], sc[256], cur[256];
    const int blk = blockIdx.x;
    const int t = threadIdx.x;
    const int nbase = blk << 8;
    if (t < 256) cnt[t] = 0;
    __syncthreads();
    const int e0 = bstart[blk], e1 = bstart[blk + 1];
    for (int p = e0 + t; p < e1; p += 1024)
        atomicAdd(&cnt[pairbuf[p] >> 17], 1);
    __syncthreads();
    int v = (t < 256) ? cnt[t] : 0;
    if (t < 256) sc[t] = v;
    __syncthreads();
    for (int off = 1; off < 256; off <<= 1) {
        int x = (t < 256 && t >= off) ? sc[t - off] : 0;
        __syncthreads();
        if (t < 256) sc[t] += x;
        __syncthreads();
    }
    if (t < 256) {
        int excl = sc[t] - v;
        int node = nbase + t;
        if (node < N_NODES) rowstart[node] = e0 + excl;
        cur[t] = e0 + excl;
    }
    __syncthreads();
    for (int p = e0 + t; p < e1; p += 1024) {
        unsigned pr = pairbuf[p];
        int pos = atomicAdd(&cur[pr >> 17], 1);
        csr_src[pos] = (int)(pr & 0x1FFFF);
    }
}

// ---------------------------------------------------------------------------
static __device__ __forceinline__ unsigned short f2bf(float f) {
    unsigned u = __float_as_uint(f);
    unsigned r = (u + 0x7fffu + ((u >> 16) & 1u)) >> 16;   // RNE
    return (unsigned short)r;
}

// Weight prep: Wt[l][side][col][k] bf16 from W[l][k][col] fp32, att -> fp16.
__global__ void prep_wt(const float* __restrict__ Wl, const float* __restrict__ Wr,
                        const float* __restrict__ att,
                        unsigned short* __restrict__ Wt, _Float16* __restrict__ atth) {
    int idx = blockIdx.x * 256 + threadIdx.x;
    if (idx < 65536) {                       // 2 layers * 2 sides * 128*128
        int l    = idx >> 15;
        int rem  = idx & 32767;
        int side = rem >> 14;
        int cw   = rem & 16383;
        int col  = cw >> 7, k = cw & 127;
        const float* W = side ? Wr : Wl;
        Wt[idx] = f2bf(W[l * 16384 + k * 128 + col]);
    } else if (idx < 65536 + 256) {
        int j = idx - 65536;
        atth[j] = (_Float16)att[j];
    }
}

// ---------------------------------------------------------------------------
// LDS-free MFMA GEMM: wave = 32 rows x 256 cols (Wl -> xl fp16, Wr -> xr fp16).
// Layer 0: A read directly from fp32 x (inline bf16 cvt); layer 1: bf16 hbf.
// ---------------------------------------------------------------------------
__global__ __launch_bounds__(256) void gemm_mfma2(
        const unsigned short* __restrict__ hbf,   // bf16 N x 128 (layer 1)
        const float* __restrict__ Afp,            // fp32 N x 128 (layer 0) or null
        const unsigned short* __restrict__ Wt,    // bf16 [2][128][128] this layer
        _Float16* __restrict__ xl, _Float16* __restrict__ xr, int n_rows) {
    const int wave = threadIdx.x >> 6;
    const int lane = threadIdx.x & 63;
    const int m = lane & 15;
    const int q = lane >> 4;
    const int r0 = (blockIdx.x * 4 + wave) * 32;

    int arow0 = r0 + m;        if (arow0 >= n_rows) arow0 = n_rows - 1;
    int arow1 = r0 + 16 + m;   if (arow1 >= n_rows) arow1 = n_rows - 1;

    floatx4 acc[2][2][8];      // [side][rt][ct]
#pragma unroll
    for (int s = 0; s < 2; ++s)
#pragma unroll
        for (int rt = 0; rt < 2; ++rt)
#pragma unroll
            for (int ct = 0; ct < 8; ++ct) acc[s][rt][ct] = (floatx4){0.f,0.f,0.f,0.f};

#pragma unroll
    for (int ks = 0; ks < 4; ++ks) {
        const int k0 = ks * 32 + q * 8;
        short8 a0, a1;
        if (Afp) {
            float4 f0 = *(const float4*)(Afp + (size_t)arow0 * 128 + k0);
            float4 f1 = *(const float4*)(Afp + (size_t)arow0 * 128 + k0 + 4);
            float4 g0 = *(const float4*)(Afp + (size_t)arow1 * 128 + k0);
            float4 g1 = *(const float4*)(Afp + (size_t)arow1 * 128 + k0 + 4);
            a0 = (short8){(short)f2bf(f0.x), (short)f2bf(f0.y), (short)f2bf(f0.z), (short)f2bf(f0.w),
                          (short)f2bf(f1.x), (short)f2bf(f1.y), (short)f2bf(f1.z), (short)f2bf(f1.w)};
            a1 = (short8){(short)f2bf(g0.x), (short)f2bf(g0.y), (short)f2bf(g0.z), (short)f2bf(g0.w),
                          (short)f2bf(g1.x), (short)f2bf(g1.y), (short)f2bf(g1.z), (short)f2bf(g1.w)};
        } else {
            a0 = *(const short8*)(hbf + (size_t)arow0 * 128 + k0);
            a1 = *(const short8*)(hbf + (size_t)arow1 * 128 + k0);
        }
#pragma unroll
        for (int s = 0; s < 2; ++s) {
#pragma unroll
            for (int ct = 0; ct < 8; ++ct) {
                short8 b = *(const short8*)(Wt + (size_t)s * 16384
                                            + (size_t)(ct * 16 + m) * 128 + k0);
                acc[s][0][ct] = __builtin_amdgcn_mfma_f32_16x16x32_bf16(a0, b, acc[s][0][ct], 0, 0, 0);
                acc[s][1][ct] = __builtin_amdgcn_mfma_f32_16x16x32_bf16(a1, b, acc[s][1][ct], 0, 0, 0);
            }
        }
    }

#pragma unroll
    for (int s = 0; s < 2; ++s) {
        _Float16* out = s ? xr : xl;
#pragma unroll
        for (int rt = 0; rt < 2; ++rt)
#pragma unroll
            for (int ct = 0; ct < 8; ++ct)
#pragma unroll
                for (int i = 0; i < 4; ++i) {
                    int row = r0 + rt * 16 + q * 4 + i;
                    if (row < n_rows)
                        out[(size_t)row * 128 + ct * 16 + m] = (_Float16)acc[s][rt][ct][i];
                }
    }
}

// ---------------------------------------------------------------------------
// Fused per-node GATv2, v8: zero LDS + 3-slot rotation-free software pipeline.
//  Body(t): [csr index load t+3] -> [row gather t+2 w/ resident index]
//           -> [consume t].  Gather cover = 2 consume bodies; index cover = 1.
//  All slot/idx register indices are static (unroll-by-3), so no v_movs and
//  no scratch.  Epilogue = shfl-butterfly (from v7, conflict-free).
// ---------------------------------------------------------------------------
union U16 { uint4 u; h2 h[4]; };

__global__ __launch_bounds__(256, 8) void gat_node8(
        const _Float16* __restrict__ xl,          // fp16 N x 128
        const _Float16* __restrict__ xr,          // fp16 N x 128
        const float* __restrict__ h_in,
        const int* __restrict__ rowstart, const int* __restrict__ csr_src,
        const _Float16* __restrict__ atth, const float* __restrict__ bias,
        const float* __restrict__ gamma, const float* __restrict__ beta,
        float* __restrict__ h_out, unsigned* __restrict__ hbf_out) {
    const int wave = threadIdx.x >> 6;
    const int lane = threadIdx.x & 63;
    const int node = blockIdx.x * 4 + wave;       // grid exact: 25000*4
    const int esub = lane >> 3;
    const int r    = lane & 7;
    const int c0   = r * 16;
    const int c    = c0 + 2 * esub;               // output channel pair

    const int p0 = rowstart[node], p1 = rowstart[node + 1];
    const int pe = p1 - 1;                        // deg >= 1 (self-loop)

    U16 xra, xrb, ata, atb;
    {
        const uint4* xp = (const uint4*)(xr + (size_t)node * 128 + c0);
        xra.u = xp[0]; xrb.u = xp[1];
        const uint4* ap = (const uint4*)(atth + c0);
        ata.u = ap[0]; atb.u = ap[1];
    }
    const float2 bi = *(const float2*)(bias + c); // epilogue const, hoisted
    const h2 ns2 = {(_Float16)NEG_SLOPE, (_Float16)NEG_SLOPE};

    const unsigned short* xls = (const unsigned short*)xl;

    float s = 0.f;
    h2 acc2[8];
#pragma unroll
    for (int j = 0; j < 8; ++j) acc2[j] = (h2){(_Float16)0.f, (_Float16)0.f};

    // dot + weighted accumulate for one 8-edge batch (two indep FMA chains)
    auto consume = [&](const U16& u0, const U16& u1, bool v) {
        float da = 0.f, db = 0.f;
#pragma unroll
        for (int qq = 0; qq < 4; ++qq) {
            h2 z  = u0.h[qq] + xra.h[qq];
            h2 lk = __builtin_elementwise_max(z, z * ns2);
            da = fdot2f(lk, ata.h[qq], da);
        }
#pragma unroll
        for (int qq = 0; qq < 4; ++qq) {
            h2 z  = u1.h[qq] + xrb.h[qq];
            h2 lk = __builtin_elementwise_max(z, z * ns2);
            db = fdot2f(lk, atb.h[qq], db);
        }
        float d = da + db;
        float alpha = d + __shfl_xor(d, 1);        // half-head pair -> head dot
        float w = v ? __expf(alpha) : 0.f;
        s += w;
        h2 w2 = {(_Float16)w, (_Float16)w};
#pragma unroll
        for (int qq = 0; qq < 4; ++qq)
            acc2[qq] = w2 * u0.h[qq] + acc2[qq];
#pragma unroll
        for (int qq = 0; qq < 4; ++qq)
            acc2[qq + 4] = w2 * u1.h[qq] + acc2[qq + 4];
    };

    // ---- prologue: indices for batches 0,1,2; gathers for batches 0,1 ----
    int pA = p0 + esub;        if (pA > pe) pA = pe;
    int pB = p0 + 8 + esub;    if (pB > pe) pB = pe;
    int pC = p0 + 16 + esub;   if (pC > pe) pC = pe;
    int i0 = csr_src[pA];
    int i1 = csr_src[pB];
    int i2 = csr_src[pC];

    U16 s0a, s0b, s1a, s1b, s2a, s2b;
    { const uint4* rp = (const uint4*)(xls + (size_t)i0 * 128 + c0); s0a.u = rp[0]; s0b.u = rp[1]; }
    { const uint4* rp = (const uint4*)(xls + (size_t)i1 * 128 + c0); s1a.u = rp[0]; s1b.u = rp[1]; }

    int pb = p0;
    for (;;) {
        // ---- body 0: consume batch t (slot0); gather t+2 (slot2, i2); csr t+3 -> i0
        {
            int pn = pb + 24 + esub; if (pn > pe) pn = pe;
            int inew = csr_src[pn];                         // batch t+3 index
            if (pb + 16 < p1) {                             // wave-uniform
                const uint4* rp = (const uint4*)(xls + (size_t)i2 * 128 + c0);
                s2a.u = rp[0]; s2b.u = rp[1];
            }
            consume(s0a, s0b, (pb + esub) < p1);
            i0 = inew;
            pb += 8; if (pb >= p1) break;
        }
        // ---- body 1: consume t (slot1); gather t+2 (slot0, i0... wait: uses i0 from 2 bodies back is WRONG -- uses i0 loaded last body) ----
        {
            int pn = pb + 24 + esub; if (pn > pe) pn = pe;
            int inew = csr_src[pn];
            if (pb + 16 < p1) {
                const uint4* rp = (const uint4*)(xls + (size_t)i0 * 128 + c0);
                s0a.u = rp[0]; s0b.u = rp[1];
            }
            consume(s1a, s1b, (pb + esub) < p1);
            i1 = inew;
            pb += 8; if (pb >= p1) break;
        }
        // ---- body 2: consume t (slot2); gather t+2 (slot1, i1); csr t+3 -> i2
        {
            int pn = pb + 24 + esub; if (pn > pe) pn = pe;
            int inew = csr_src[pn];
            if (pb + 16 < p1) {
                const uint4* rp = (const uint4*)(xls + (size_t)i1 * 128 + c0);
                s1a.u = rp[0]; s1b.u = rp[1];
            }
            consume(s2a, s2b, (pb + esub) < p1);
            i2 = inew;
            pb += 8; if (pb >= p1) break;
        }
    }

    // ---- per-head softmax denominator: sum s across esub lanes ----
    float ssum = s;
    ssum += __shfl_xor(ssum, 8);
    ssum += __shfl_xor(ssum, 16);
    ssum += __shfl_xor(ssum, 32);
    // every lane now holds S for head (r>>1) == head of its output channels

    // ---- cross-esub butterfly reduction of acc2 (recursive halving) ----
    const bool sel0 = (esub & 1) != 0;
    const bool sel1 = ((esub >> 1) & 1) != 0;
    const bool sel2 = ((esub >> 2) & 1) != 0;
    h2 b4[4];
#pragma unroll
    for (int k = 0; k < 4; ++k) {
        h2 keep = sel0 ? acc2[2 * k + 1] : acc2[2 * k];
        h2 send = sel0 ? acc2[2 * k]     : acc2[2 * k + 1];
        b4[k] = keep + shfl_xor_h2(send, 8);
    }
    h2 c2[2];
#pragma unroll
    for (int k = 0; k < 2; ++k) {
        h2 keep = sel1 ? b4[2 * k + 1] : b4[2 * k];
        h2 send = sel1 ? b4[2 * k]     : b4[2 * k + 1];
        c2[k] = keep + shfl_xor_h2(send, 16);
    }
    h2 keepf = sel2 ? c2[1] : c2[0];
    h2 sendf = sel2 ? c2[0] : c2[1];
    h2 tot = keepf + shfl_xor_h2(sendf, 32);
    // tot = channels (c, c+1) summed over all 8 edge slots

    const float invS = 1.f / ssum;
    float g0 = (float)tot[0] * invS + bi.x;
    float g1 = (float)tot[1] * invS + bi.y;

    // issue remaining epilogue loads before the LN allreduce (latency cover)
    const float2 ga = *(const float2*)(gamma + c);
    const float2 be = *(const float2*)(beta + c);
    const float2 hv = *(const float2*)(h_in + (size_t)node * 128 + c);

    // ---- LayerNorm over 128 channels (full-wave allreduce) ----
    float sum = g0 + g1, sq = g0 * g0 + g1 * g1;
#pragma unroll
    for (int off = 1; off < 64; off <<= 1) {
        sum += __shfl_xor(sum, off);
        sq  += __shfl_xor(sq, off);
    }
    float mu   = sum * (1.f / 128.f);
    float var  = sq * (1.f / 128.f) - mu * mu;
    float rstd = rsqrtf(var + LN_EPS);
    float y0 = (g0 - mu) * rstd * ga.x + be.x;
    float y1 = (g1 - mu) * rstd * ga.y + be.y;
    float e0 = (y0 > 0.f) ? y0 : (__expf(y0) - 1.f);
    float e1 = (y1 > 0.f) ? y1 : (__expf(y1) - 1.f);

    float2 o;
    o.x = hv.x + e0;
    o.y = hv.y + e1;
    *(float2*)(h_out + (size_t)node * 128 + c) = o;
    if (hbf_out) {                                // layer 0: bf16 copy for next GEMM
        unsigned pk = (unsigned)f2bf(o.x) | ((unsigned)f2bf(o.y) << 16);
        hbf_out[(size_t)node * 64 + (c >> 1)] = pk;
    }
}

// ---------------------------------------------------------------------------
extern "C" void kernel_launch(void* const* d_in, const int* in_sizes, int n_in,
                              void* d_out, int out_size, void* d_ws, size_t ws_size,
                              hipStream_t stream) {
    const float* x     = (const float*)d_in[0];
    const int*   eidx  = (const int*)d_in[1];   // (2, E)
    const float* Wl    = (const float*)d_in[2]; // (L,128,128)
    const float* Wr    = (const float*)d_in[3];
    const float* att   = (const float*)d_in[4]; // (L,4,32) -> stride 128
    const float* bias  = (const float*)d_in[5];
    const float* gamma = (const float*)d_in[6];
    const float* beta  = (const float*)d_in[7];
    float* out = (float*)d_out;

    char* ws = (char*)d_ws;
    _Float16* xl = (_Float16*)ws;              ws += (size_t)N_NODES * 128 * 2;
    _Float16* xr = (_Float16*)ws;              ws += (size_t)N_NODES * 128 * 2;
    float* h1 = (float*)ws;                    ws += (size_t)N_NODES * 128 * 4;
    unsigned short* hbf = (unsigned short*)ws; ws += (size_t)N_NODES * 128 * 2;
    unsigned short* Wt  = (unsigned short*)ws; ws += (size_t)65536 * 2;
    _Float16* atth = (_Float16*)ws;            ws += 256 * 2;
    unsigned* pairbuf = (unsigned*)ws;         ws += (size_t)E2 * 4;
    int* tcnt     = (int*)ws; ws += (size_t)NTIL * NB * 4;
    int* toff     = (int*)ws; ws += (size_t)NTIL * NB * 4;
    int* bcnt     = (int*)ws; ws += (NB + 1) * 4;
    int* bstart   = (int*)ws; ws += (NB + 1) * 4;
    int* rowstart = (int*)ws; ws += (size_t)(N_NODES + 4) * 4;
    int* csr_src  = (int*)ws; ws += (size_t)E2 * 4;

    const int* edge_src = eidx;
    const int* edge_dst = eidx + E_EDGES;

    // ---- prep: weights -> transposed bf16, att -> fp16 ----
    prep_wt<<<257, 256, 0, stream>>>(Wl, Wr, att, Wt, atth);

    // ---- CSR build (no global atomics) ----
    tile_count<<<NTIL, 1024, 0, stream>>>(edge_dst, tcnt);
    col_scan<<<NB, 256, 0, stream>>>(tcnt, toff, bcnt);
    bucket_scan<<<1, 512, 0, stream>>>(bcnt, bstart, rowstart);
    tile_scatter<<<NTIL, 1024, 0, stream>>>(edge_src, edge_dst, bstart, toff, pairbuf);
    bucketize<<<NB, 1024, 0, stream>>>(pairbuf, bstart, rowstart, csr_src);

    // ---- two GATv2 layers ----
    const int gemm_gx = (N_NODES + 127) / 128;   // 782
    for (int l = 0; l < 2; ++l) {
        const float* hin  = (l == 0) ? x  : h1;
        float*       hout = (l == 1) ? out : h1;
        gemm_mfma2<<<gemm_gx, 256, 0, stream>>>(
            hbf, (l == 0) ? x : nullptr, Wt + (size_t)l * 32768, xl, xr, N_NODES);
        gat_node8<<<N_NODES / 4, 256, 0, stream>>>(
            xl, xr, hin, rowstart, csr_src,
            atth + l * 128, bias + l * 128, gamma + l * 128, beta + l * 128,
            hout, (l == 0) ? (unsigned*)hbf : nullptr);
    }
}

// Round 3
// 398.909 us; speedup vs baseline: 1.8253x; 1.8253x over previous
//
#include <hip/hip_runtime.h>
#include <hip/hip_fp16.h>
#include <math.h>

#define N_NODES 100000
#define D_FEAT  128
#define E_EDGES 1600000
#define E2      (E_EDGES + N_NODES)   /* 1,700,000 with self-loops */
#define NEG_SLOPE 0.2f
#define LN_EPS    1e-5f

#define NB   391                      /* buckets of 256 nodes: d >> 8 */
#define TS   8192                     /* edges per tile */
#define NTIL ((E2 + TS - 1) / TS)     /* 208 */

typedef __attribute__((ext_vector_type(8))) short short8;
typedef __attribute__((ext_vector_type(4))) float floatx4;
typedef _Float16 h2 __attribute__((ext_vector_type(2)));   // packed half pair

static __device__ __forceinline__ float fdot2f(h2 a, h2 b, float c) {
#if __has_builtin(__builtin_amdgcn_fdot2)
    return __builtin_amdgcn_fdot2(a, b, c, false);
#else
    return (float)a[0] * (float)b[0] + (float)a[1] * (float)b[1] + c;
#endif
}

static __device__ __forceinline__ h2 shfl_xor_h2(h2 v, int off) {
    int i = __builtin_bit_cast(int, v);
    i = __shfl_xor(i, off);
    return __builtin_bit_cast(h2, i);
}

// ---------------------------------------------------------------------------
// CSR build, zero global atomics:
//  1) tile_count : per-tile LDS hist -> tcnt[tile][bucket]
//  2) col_scan   : per-bucket scan over tiles -> toff, bucket totals bcnt
//  3) bucket_scan: scan bucket totals -> bstart; rowstart[N]=E2
//  4) tile_scatter: deterministic dest = bstart[b]+toff[tile][b]+LDS-rank,
//                   packed pair (src | dst_low<<17) -> pairbuf
//  5) bucketize  : per bucket (256 nodes, 1024 thr) count+scan+scatter
// ---------------------------------------------------------------------------
__global__ __launch_bounds__(1024) void tile_count(const int* __restrict__ edge_dst,
                                                   int* __restrict__ tcnt) {
    __shared__ int h[NB];
    const int t = threadIdx.x;
    if (t < NB) h[t] = 0;
    __syncthreads();
    const int base = blockIdx.x * TS;
#pragma unroll
    for (int j = 0; j < TS / 1024; ++j) {
        int i = base + j * 1024 + t;
        if (i < E2) {
            int d = (i < E_EDGES) ? edge_dst[i] : (i - E_EDGES);
            atomicAdd(&h[d >> 8], 1);
        }
    }
    __syncthreads();
    if (t < NB) tcnt[blockIdx.x * NB + t] = h[t];
}

__global__ __launch_bounds__(256) void col_scan(const int* __restrict__ tcnt,
                                                int* __restrict__ toff,
                                                int* __restrict__ bcnt) {
    __shared__ int s[256];
    const int b = blockIdx.x;
    const int t = threadIdx.x;
    int v = (t < NTIL) ? tcnt[t * NB + b] : 0;
    s[t] = v;
    __syncthreads();
    for (int off = 1; off < 256; off <<= 1) {
        int x = (t >= off) ? s[t - off] : 0;
        __syncthreads();
        s[t] += x;
        __syncthreads();
    }
    if (t < NTIL) toff[t * NB + b] = s[t] - v;   // exclusive
    if (t == 255) bcnt[b] = s[255];
}

__global__ __launch_bounds__(512) void bucket_scan(const int* __restrict__ bcnt,
                                                   int* __restrict__ bstart,
                                                   int* __restrict__ rowstart) {
    __shared__ int s[512];
    const int t = threadIdx.x;
    int v = (t < NB) ? bcnt[t] : 0;
    s[t] = v;
    __syncthreads();
    for (int off = 1; off < 512; off <<= 1) {
        int x = (t >= off) ? s[t - off] : 0;
        __syncthreads();
        s[t] += x;
        __syncthreads();
    }
    if (t <= NB) bstart[t] = s[t] - v;   // t==NB: total == E2
    if (t == 0) rowstart[N_NODES] = E2;
}

__global__ __launch_bounds__(1024) void tile_scatter(const int* __restrict__ edge_src,
                                                     const int* __restrict__ edge_dst,
                                                     const int* __restrict__ bstart,
                                                     const int* __restrict__ toff,
                                                     unsigned* __restrict__ pairbuf) {
    __shared__ int base[NB];
    __shared__ int cur[NB];
    const int t = threadIdx.x;
    if (t < NB) { base[t] = bstart[t] + toff[blockIdx.x * NB + t]; cur[t] = 0; }
    __syncthreads();
    const int tb = blockIdx.x * TS;
#pragma unroll
    for (int j = 0; j < TS / 1024; ++j) {
        int i = tb + j * 1024 + t;
        if (i < E2) {
            int d, sr;
            if (i < E_EDGES) { d = edge_dst[i]; sr = edge_src[i]; }
            else             { d = i - E_EDGES; sr = d; }
            int b = d >> 8;
            int rank = atomicAdd(&cur[b], 1);
            pairbuf[base[b] + rank] = (unsigned)sr | ((unsigned)(d & 255) << 17);
        }
    }
}

__global__ __launch_bounds__(1024) void bucketize(const unsigned* __restrict__ pairbuf,
                                                  const int* __restrict__ bstart,
                                                  int* __restrict__ rowstart,
                                                  int* __restrict__ csr_src) {
    __shared__ int cnt[256], sc[256], cur[256];
    const int blk = blockIdx.x;
    const int t = threadIdx.x;
    const int nbase = blk << 8;
    if (t < 256) cnt[t] = 0;
    __syncthreads();
    const int e0 = bstart[blk], e1 = bstart[blk + 1];
    for (int p = e0 + t; p < e1; p += 1024)
        atomicAdd(&cnt[pairbuf[p] >> 17], 1);
    __syncthreads();
    int v = (t < 256) ? cnt[t] : 0;
    if (t < 256) sc[t] = v;
    __syncthreads();
    for (int off = 1; off < 256; off <<= 1) {
        int x = (t < 256 && t >= off) ? sc[t - off] : 0;
        __syncthreads();
        if (t < 256) sc[t] += x;
        __syncthreads();
    }
    if (t < 256) {
        int excl = sc[t] - v;
        int node = nbase + t;
        if (node < N_NODES) rowstart[node] = e0 + excl;
        cur[t] = e0 + excl;
    }
    __syncthreads();
    for (int p = e0 + t; p < e1; p += 1024) {
        unsigned pr = pairbuf[p];
        int pos = atomicAdd(&cur[pr >> 17], 1);
        csr_src[pos] = (int)(pr & 0x1FFFF);
    }
}

// ---------------------------------------------------------------------------
static __device__ __forceinline__ unsigned short f2bf(float f) {
    unsigned u = __float_as_uint(f);
    unsigned r = (u + 0x7fffu + ((u >> 16) & 1u)) >> 16;   // RNE
    return (unsigned short)r;
}

// Weight prep: Wt[l][side][col][k] bf16 from W[l][k][col] fp32, att -> fp16.
__global__ void prep_wt(const float* __restrict__ Wl, const float* __restrict__ Wr,
                        const float* __restrict__ att,
                        unsigned short* __restrict__ Wt, _Float16* __restrict__ atth) {
    int idx = blockIdx.x * 256 + threadIdx.x;
    if (idx < 65536) {                       // 2 layers * 2 sides * 128*128
        int l    = idx >> 15;
        int rem  = idx & 32767;
        int side = rem >> 14;
        int cw   = rem & 16383;
        int col  = cw >> 7, k = cw & 127;
        const float* W = side ? Wr : Wl;
        Wt[idx] = f2bf(W[l * 16384 + k * 128 + col]);
    } else if (idx < 65536 + 256) {
        int j = idx - 65536;
        atth[j] = (_Float16)att[j];
    }
}

// ---------------------------------------------------------------------------
// LDS-free MFMA GEMM: wave = 32 rows x 256 cols (Wl -> xl fp16, Wr -> xr fp16).
// Layer 0: A read directly from fp32 x (inline bf16 cvt); layer 1: bf16 hbf.
// ---------------------------------------------------------------------------
__global__ __launch_bounds__(256) void gemm_mfma2(
        const unsigned short* __restrict__ hbf,   // bf16 N x 128 (layer 1)
        const float* __restrict__ Afp,            // fp32 N x 128 (layer 0) or null
        const unsigned short* __restrict__ Wt,    // bf16 [2][128][128] this layer
        _Float16* __restrict__ xl, _Float16* __restrict__ xr, int n_rows) {
    const int wave = threadIdx.x >> 6;
    const int lane = threadIdx.x & 63;
    const int m = lane & 15;
    const int q = lane >> 4;
    const int r0 = (blockIdx.x * 4 + wave) * 32;

    int arow0 = r0 + m;        if (arow0 >= n_rows) arow0 = n_rows - 1;
    int arow1 = r0 + 16 + m;   if (arow1 >= n_rows) arow1 = n_rows - 1;

    floatx4 acc[2][2][8];      // [side][rt][ct]
#pragma unroll
    for (int s = 0; s < 2; ++s)
#pragma unroll
        for (int rt = 0; rt < 2; ++rt)
#pragma unroll
            for (int ct = 0; ct < 8; ++ct) acc[s][rt][ct] = (floatx4){0.f,0.f,0.f,0.f};

#pragma unroll
    for (int ks = 0; ks < 4; ++ks) {
        const int k0 = ks * 32 + q * 8;
        short8 a0, a1;
        if (Afp) {
            float4 f0 = *(const float4*)(Afp + (size_t)arow0 * 128 + k0);
            float4 f1 = *(const float4*)(Afp + (size_t)arow0 * 128 + k0 + 4);
            float4 g0 = *(const float4*)(Afp + (size_t)arow1 * 128 + k0);
            float4 g1 = *(const float4*)(Afp + (size_t)arow1 * 128 + k0 + 4);
            a0 = (short8){(short)f2bf(f0.x), (short)f2bf(f0.y), (short)f2bf(f0.z), (short)f2bf(f0.w),
                          (short)f2bf(f1.x), (short)f2bf(f1.y), (short)f2bf(f1.z), (short)f2bf(f1.w)};
            a1 = (short8){(short)f2bf(g0.x), (short)f2bf(g0.y), (short)f2bf(g0.z), (short)f2bf(g0.w),
                          (short)f2bf(g1.x), (short)f2bf(g1.y), (short)f2bf(g1.z), (short)f2bf(g1.w)};
        } else {
            a0 = *(const short8*)(hbf + (size_t)arow0 * 128 + k0);
            a1 = *(const short8*)(hbf + (size_t)arow1 * 128 + k0);
        }
#pragma unroll
        for (int s = 0; s < 2; ++s) {
#pragma unroll
            for (int ct = 0; ct < 8; ++ct) {
                short8 b = *(const short8*)(Wt + (size_t)s * 16384
                                            + (size_t)(ct * 16 + m) * 128 + k0);
                acc[s][0][ct] = __builtin_amdgcn_mfma_f32_16x16x32_bf16(a0, b, acc[s][0][ct], 0, 0, 0);
                acc[s][1][ct] = __builtin_amdgcn_mfma_f32_16x16x32_bf16(a1, b, acc[s][1][ct], 0, 0, 0);
            }
        }
    }

#pragma unroll
    for (int s = 0; s < 2; ++s) {
        _Float16* out = s ? xr : xl;
#pragma unroll
        for (int rt = 0; rt < 2; ++rt)
#pragma unroll
            for (int ct = 0; ct < 8; ++ct)
#pragma unroll
                for (int i = 0; i < 4; ++i) {
                    int row = r0 + rt * 16 + q * 4 + i;
                    if (row < n_rows)
                        out[(size_t)row * 128 + ct * 16 + m] = (_Float16)acc[s][rt][ct][i];
                }
    }
}

// ---------------------------------------------------------------------------
// Fused per-node GATv2, v9: v8's 3-slot rotation-free pipeline WITHOUT the
// occupancy clamp (v8's __launch_bounds__(256,8) forced <=64 VGPR and spilled
// the whole pipeline state to scratch: WRITE_SIZE 75->752 MB).  Plain
// __launch_bounds__(256) lets VGPR float (~80): no scratch, 2-body gather
// cover with resident indices.
// ---------------------------------------------------------------------------
union U16 { uint4 u; h2 h[4]; };

__global__ __launch_bounds__(256) void gat_node9(
        const _Float16* __restrict__ xl,          // fp16 N x 128
        const _Float16* __restrict__ xr,          // fp16 N x 128
        const float* __restrict__ h_in,
        const int* __restrict__ rowstart, const int* __restrict__ csr_src,
        const _Float16* __restrict__ atth, const float* __restrict__ bias,
        const float* __restrict__ gamma, const float* __restrict__ beta,
        float* __restrict__ h_out, unsigned* __restrict__ hbf_out) {
    const int wave = threadIdx.x >> 6;
    const int lane = threadIdx.x & 63;
    const int node = blockIdx.x * 4 + wave;       // grid exact: 25000*4
    const int esub = lane >> 3;
    const int r    = lane & 7;
    const int c0   = r * 16;
    const int c    = c0 + 2 * esub;               // output channel pair

    const int p0 = rowstart[node], p1 = rowstart[node + 1];
    const int pe = p1 - 1;                        // deg >= 1 (self-loop)

    U16 xra, xrb, ata, atb;
    {
        const uint4* xp = (const uint4*)(xr + (size_t)node * 128 + c0);
        xra.u = xp[0]; xrb.u = xp[1];
        const uint4* ap = (const uint4*)(atth + c0);
        ata.u = ap[0]; atb.u = ap[1];
    }
    const float2 bi = *(const float2*)(bias + c); // epilogue const, hoisted
    const h2 ns2 = {(_Float16)NEG_SLOPE, (_Float16)NEG_SLOPE};

    const unsigned short* xls = (const unsigned short*)xl;

    float s = 0.f;
    h2 acc2[8];
#pragma unroll
    for (int j = 0; j < 8; ++j) acc2[j] = (h2){(_Float16)0.f, (_Float16)0.f};

    // dot + weighted accumulate for one 8-edge batch (two indep FMA chains)
    auto consume = [&](const U16& u0, const U16& u1, bool v) {
        float da = 0.f, db = 0.f;
#pragma unroll
        for (int qq = 0; qq < 4; ++qq) {
            h2 z  = u0.h[qq] + xra.h[qq];
            h2 lk = __builtin_elementwise_max(z, z * ns2);
            da = fdot2f(lk, ata.h[qq], da);
        }
#pragma unroll
        for (int qq = 0; qq < 4; ++qq) {
            h2 z  = u1.h[qq] + xrb.h[qq];
            h2 lk = __builtin_elementwise_max(z, z * ns2);
            db = fdot2f(lk, atb.h[qq], db);
        }
        float d = da + db;
        float alpha = d + __shfl_xor(d, 1);        // half-head pair -> head dot
        float w = v ? __expf(alpha) : 0.f;
        s += w;
        h2 w2 = {(_Float16)w, (_Float16)w};
#pragma unroll
        for (int qq = 0; qq < 4; ++qq)
            acc2[qq] = w2 * u0.h[qq] + acc2[qq];
#pragma unroll
        for (int qq = 0; qq < 4; ++qq)
            acc2[qq + 4] = w2 * u1.h[qq] + acc2[qq + 4];
    };

    // ---- prologue: indices for batches 0,1,2; gathers for batches 0,1 ----
    int pA = p0 + esub;        if (pA > pe) pA = pe;
    int pB = p0 + 8 + esub;    if (pB > pe) pB = pe;
    int pC = p0 + 16 + esub;   if (pC > pe) pC = pe;
    int i0 = csr_src[pA];
    int i1 = csr_src[pB];
    int i2 = csr_src[pC];

    U16 s0a, s0b, s1a, s1b, s2a, s2b;
    { const uint4* rp = (const uint4*)(xls + (size_t)i0 * 128 + c0); s0a.u = rp[0]; s0b.u = rp[1]; }
    { const uint4* rp = (const uint4*)(xls + (size_t)i1 * 128 + c0); s1a.u = rp[0]; s1b.u = rp[1]; }

    int pb = p0;
    for (;;) {
        // ---- body 0: csr t+3 -> i0; gather t+2 via i2 -> slot2; consume slot0
        {
            int pn = pb + 24 + esub; if (pn > pe) pn = pe;
            int inew = csr_src[pn];                         // batch t+3 index
            if (pb + 16 < p1) {                             // wave-uniform
                const uint4* rp = (const uint4*)(xls + (size_t)i2 * 128 + c0);
                s2a.u = rp[0]; s2b.u = rp[1];
            }
            consume(s0a, s0b, (pb + esub) < p1);
            i0 = inew;
            pb += 8; if (pb >= p1) break;
        }
        // ---- body 1: csr t+3 -> i1; gather t+2 via i0 -> slot0; consume slot1
        {
            int pn = pb + 24 + esub; if (pn > pe) pn = pe;
            int inew = csr_src[pn];
            if (pb + 16 < p1) {
                const uint4* rp = (const uint4*)(xls + (size_t)i0 * 128 + c0);
                s0a.u = rp[0]; s0b.u = rp[1];
            }
            consume(s1a, s1b, (pb + esub) < p1);
            i1 = inew;
            pb += 8; if (pb >= p1) break;
        }
        // ---- body 2: csr t+3 -> i2; gather t+2 via i1 -> slot1; consume slot2
        {
            int pn = pb + 24 + esub; if (pn > pe) pn = pe;
            int inew = csr_src[pn];
            if (pb + 16 < p1) {
                const uint4* rp = (const uint4*)(xls + (size_t)i1 * 128 + c0);
                s1a.u = rp[0]; s1b.u = rp[1];
            }
            consume(s2a, s2b, (pb + esub) < p1);
            i2 = inew;
            pb += 8; if (pb >= p1) break;
        }
    }

    // ---- per-head softmax denominator: sum s across esub lanes ----
    float ssum = s;
    ssum += __shfl_xor(ssum, 8);
    ssum += __shfl_xor(ssum, 16);
    ssum += __shfl_xor(ssum, 32);
    // every lane now holds S for head (r>>1) == head of its output channels

    // ---- cross-esub butterfly reduction of acc2 (recursive halving) ----
    const bool sel0 = (esub & 1) != 0;
    const bool sel1 = ((esub >> 1) & 1) != 0;
    const bool sel2 = ((esub >> 2) & 1) != 0;
    h2 b4[4];
#pragma unroll
    for (int k = 0; k < 4; ++k) {
        h2 keep = sel0 ? acc2[2 * k + 1] : acc2[2 * k];
        h2 send = sel0 ? acc2[2 * k]     : acc2[2 * k + 1];
        b4[k] = keep + shfl_xor_h2(send, 8);
    }
    h2 c2[2];
#pragma unroll
    for (int k = 0; k < 2; ++k) {
        h2 keep = sel1 ? b4[2 * k + 1] : b4[2 * k];
        h2 send = sel1 ? b4[2 * k]     : b4[2 * k + 1];
        c2[k] = keep + shfl_xor_h2(send, 16);
    }
    h2 keepf = sel2 ? c2[1] : c2[0];
    h2 sendf = sel2 ? c2[0] : c2[1];
    h2 tot = keepf + shfl_xor_h2(sendf, 32);
    // tot = channels (c, c+1) summed over all 8 edge slots

    const float invS = 1.f / ssum;
    float g0 = (float)tot[0] * invS + bi.x;
    float g1 = (float)tot[1] * invS + bi.y;

    // issue remaining epilogue loads before the LN allreduce (latency cover)
    const float2 ga = *(const float2*)(gamma + c);
    const float2 be = *(const float2*)(beta + c);
    const float2 hv = *(const float2*)(h_in + (size_t)node * 128 + c);

    // ---- LayerNorm over 128 channels (full-wave allreduce) ----
    float sum = g0 + g1, sq = g0 * g0 + g1 * g1;
#pragma unroll
    for (int off = 1; off < 64; off <<= 1) {
        sum += __shfl_xor(sum, off);
        sq  += __shfl_xor(sq, off);
    }
    float mu   = sum * (1.f / 128.f);
    float var  = sq * (1.f / 128.f) - mu * mu;
    float rstd = rsqrtf(var + LN_EPS);
    float y0 = (g0 - mu) * rstd * ga.x + be.x;
    float y1 = (g1 - mu) * rstd * ga.y + be.y;
    float e0 = (y0 > 0.f) ? y0 : (__expf(y0) - 1.f);
    float e1 = (y1 > 0.f) ? y1 : (__expf(y1) - 1.f);

    float2 o;
    o.x = hv.x + e0;
    o.y = hv.y + e1;
    *(float2*)(h_out + (size_t)node * 128 + c) = o;
    if (hbf_out) {                                // layer 0: bf16 copy for next GEMM
        unsigned pk = (unsigned)f2bf(o.x) | ((unsigned)f2bf(o.y) << 16);
        hbf_out[(size_t)node * 64 + (c >> 1)] = pk;
    }
}

// ---------------------------------------------------------------------------
extern "C" void kernel_launch(void* const* d_in, const int* in_sizes, int n_in,
                              void* d_out, int out_size, void* d_ws, size_t ws_size,
                              hipStream_t stream) {
    const float* x     = (const float*)d_in[0];
    const int*   eidx  = (const int*)d_in[1];   // (2, E)
    const float* Wl    = (const float*)d_in[2]; // (L,128,128)
    const float* Wr    = (const float*)d_in[3];
    const float* att   = (const float*)d_in[4]; // (L,4,32) -> stride 128
    const float* bias  = (const float*)d_in[5];
    const float* gamma = (const float*)d_in[6];
    const float* beta  = (const float*)d_in[7];
    float* out = (float*)d_out;

    char* ws = (char*)d_ws;
    _Float16* xl = (_Float16*)ws;              ws += (size_t)N_NODES * 128 * 2;
    _Float16* xr = (_Float16*)ws;              ws += (size_t)N_NODES * 128 * 2;
    float* h1 = (float*)ws;                    ws += (size_t)N_NODES * 128 * 4;
    unsigned short* hbf = (unsigned short*)ws; ws += (size_t)N_NODES * 128 * 2;
    unsigned short* Wt  = (unsigned short*)ws; ws += (size_t)65536 * 2;
    _Float16* atth = (_Float16*)ws;            ws += 256 * 2;
    unsigned* pairbuf = (unsigned*)ws;         ws += (size_t)E2 * 4;
    int* tcnt     = (int*)ws; ws += (size_t)NTIL * NB * 4;
    int* toff     = (int*)ws; ws += (size_t)NTIL * NB * 4;
    int* bcnt     = (int*)ws; ws += (NB + 1) * 4;
    int* bstart   = (int*)ws; ws += (NB + 1) * 4;
    int* rowstart = (int*)ws; ws += (size_t)(N_NODES + 4) * 4;
    int* csr_src  = (int*)ws; ws += (size_t)E2 * 4;

    const int* edge_src = eidx;
    const int* edge_dst = eidx + E_EDGES;

    // ---- prep: weights -> transposed bf16, att -> fp16 ----
    prep_wt<<<257, 256, 0, stream>>>(Wl, Wr, att, Wt, atth);

    // ---- CSR build (no global atomics) ----
    tile_count<<<NTIL, 1024, 0, stream>>>(edge_dst, tcnt);
    col_scan<<<NB, 256, 0, stream>>>(tcnt, toff, bcnt);
    bucket_scan<<<1, 512, 0, stream>>>(bcnt, bstart, rowstart);
    tile_scatter<<<NTIL, 1024, 0, stream>>>(edge_src, edge_dst, bstart, toff, pairbuf);
    bucketize<<<NB, 1024, 0, stream>>>(pairbuf, bstart, rowstart, csr_src);

    // ---- two GATv2 layers ----
    const int gemm_gx = (N_NODES + 127) / 128;   // 782
    for (int l = 0; l < 2; ++l) {
        const float* hin  = (l == 0) ? x  : h1;
        float*       hout = (l == 1) ? out : h1;
        gemm_mfma2<<<gemm_gx, 256, 0, stream>>>(
            hbf, (l == 0) ? x : nullptr, Wt + (size_t)l * 32768, xl, xr, N_NODES);
        gat_node9<<<N_NODES / 4, 256, 0, stream>>>(
            xl, xr, hin, rowstart, csr_src,
            atth + l * 128, bias + l * 128, gamma + l * 128, beta + l * 128,
            hout, (l == 0) ? (unsigned*)hbf : nullptr);
    }
}

// Round 4
// 388.060 us; speedup vs baseline: 1.8763x; 1.0280x over previous
//
#include <hip/hip_runtime.h>
#include <hip/hip_fp16.h>
#include <math.h>

#define N_NODES 100000
#define D_FEAT  128
#define E_EDGES 1600000
#define E2      (E_EDGES + N_NODES)   /* 1,700,000 with self-loops */
#define NEG_SLOPE 0.2f
#define LN_EPS    1e-5f

#define NB   391                      /* buckets of 256 nodes: d >> 8 */
#define TS   8192                     /* edges per tile */
#define NTIL ((E2 + TS - 1) / TS)     /* 208 */

typedef __attribute__((ext_vector_type(4))) float floatx4;
typedef _Float16 h2 __attribute__((ext_vector_type(2)));   // packed half pair
typedef _Float16 h8 __attribute__((ext_vector_type(8)));   // fp16 MFMA fragment

static __device__ __forceinline__ float fdot2f(h2 a, h2 b, float c) {
#if __has_builtin(__builtin_amdgcn_fdot2)
    return __builtin_amdgcn_fdot2(a, b, c, false);
#else
    return (float)a[0] * (float)b[0] + (float)a[1] * (float)b[1] + c;
#endif
}

static __device__ __forceinline__ h2 shfl_xor_h2(h2 v, int off) {
    int i = __builtin_bit_cast(int, v);
    i = __shfl_xor(i, off);
    return __builtin_bit_cast(h2, i);
}

// ---------------------------------------------------------------------------
// CSR build, zero global atomics (unchanged from v6/v9):
// ---------------------------------------------------------------------------
__global__ __launch_bounds__(1024) void tile_count(const int* __restrict__ edge_dst,
                                                   int* __restrict__ tcnt) {
    __shared__ int h[NB];
    const int t = threadIdx.x;
    if (t < NB) h[t] = 0;
    __syncthreads();
    const int base = blockIdx.x * TS;
#pragma unroll
    for (int j = 0; j < TS / 1024; ++j) {
        int i = base + j * 1024 + t;
        if (i < E2) {
            int d = (i < E_EDGES) ? edge_dst[i] : (i - E_EDGES);
            atomicAdd(&h[d >> 8], 1);
        }
    }
    __syncthreads();
    if (t < NB) tcnt[blockIdx.x * NB + t] = h[t];
}

__global__ __launch_bounds__(256) void col_scan(const int* __restrict__ tcnt,
                                                int* __restrict__ toff,
                                                int* __restrict__ bcnt) {
    __shared__ int s[256];
    const int b = blockIdx.x;
    const int t = threadIdx.x;
    int v = (t < NTIL) ? tcnt[t * NB + b] : 0;
    s[t] = v;
    __syncthreads();
    for (int off = 1; off < 256; off <<= 1) {
        int x = (t >= off) ? s[t - off] : 0;
        __syncthreads();
        s[t] += x;
        __syncthreads();
    }
    if (t < NTIL) toff[t * NB + b] = s[t] - v;   // exclusive
    if (t == 255) bcnt[b] = s[255];
}

__global__ __launch_bounds__(512) void bucket_scan(const int* __restrict__ bcnt,
                                                   int* __restrict__ bstart,
                                                   int* __restrict__ rowstart) {
    __shared__ int s[512];
    const int t = threadIdx.x;
    int v = (t < NB) ? bcnt[t] : 0;
    s[t] = v;
    __syncthreads();
    for (int off = 1; off < 512; off <<= 1) {
        int x = (t >= off) ? s[t - off] : 0;
        __syncthreads();
        s[t] += x;
        __syncthreads();
    }
    if (t <= NB) bstart[t] = s[t] - v;   // t==NB: total == E2
    if (t == 0) rowstart[N_NODES] = E2;
}

__global__ __launch_bounds__(1024) void tile_scatter(const int* __restrict__ edge_src,
                                                     const int* __restrict__ edge_dst,
                                                     const int* __restrict__ bstart,
                                                     const int* __restrict__ toff,
                                                     unsigned* __restrict__ pairbuf) {
    __shared__ int base[NB];
    __shared__ int cur[NB];
    const int t = threadIdx.x;
    if (t < NB) { base[t] = bstart[t] + toff[blockIdx.x * NB + t]; cur[t] = 0; }
    __syncthreads();
    const int tb = blockIdx.x * TS;
#pragma unroll
    for (int j = 0; j < TS / 1024; ++j) {
        int i = tb + j * 1024 + t;
        if (i < E2) {
            int d, sr;
            if (i < E_EDGES) { d = edge_dst[i]; sr = edge_src[i]; }
            else             { d = i - E_EDGES; sr = d; }
            int b = d >> 8;
            int rank = atomicAdd(&cur[b], 1);
            pairbuf[base[b] + rank] = (unsigned)sr | ((unsigned)(d & 255) << 17);
        }
    }
}

__global__ __launch_bounds__(1024) void bucketize(const unsigned* __restrict__ pairbuf,
                                                  const int* __restrict__ bstart,
                                                  int* __restrict__ rowstart,
                                                  int* __restrict__ csr_src) {
    __shared__ int cnt[256], sc[256], cur[256];
    const int blk = blockIdx.x;
    const int t = threadIdx.x;
    const int nbase = blk << 8;
    if (t < 256) cnt[t] = 0;
    __syncthreads();
    const int e0 = bstart[blk], e1 = bstart[blk + 1];
    for (int p = e0 + t; p < e1; p += 1024)
        atomicAdd(&cnt[pairbuf[p] >> 17], 1);
    __syncthreads();
    int v = (t < 256) ? cnt[t] : 0;
    if (t < 256) sc[t] = v;
    __syncthreads();
    for (int off = 1; off < 256; off <<= 1) {
        int x = (t < 256 && t >= off) ? sc[t - off] : 0;
        __syncthreads();
        if (t < 256) sc[t] += x;
        __syncthreads();
    }
    if (t < 256) {
        int excl = sc[t] - v;
        int node = nbase + t;
        if (node < N_NODES) rowstart[node] = e0 + excl;
        cur[t] = e0 + excl;
    }
    __syncthreads();
    for (int p = e0 + t; p < e1; p += 1024) {
        unsigned pr = pairbuf[p];
        int pos = atomicAdd(&cur[pr >> 17], 1);
        csr_src[pos] = (int)(pr & 0x1FFFF);
    }
}

// ---------------------------------------------------------------------------
// Weight prep: Wt[l][side][col][k] fp16 from W[l][k][col] fp32, att -> fp16.
// fp16 weights (10-bit mantissa) >= bf16 precision; values |W| < 1 in-range.
// ---------------------------------------------------------------------------
__global__ void prep_wt(const float* __restrict__ Wl, const float* __restrict__ Wr,
                        const float* __restrict__ att,
                        _Float16* __restrict__ Wt, _Float16* __restrict__ atth) {
    int idx = blockIdx.x * 256 + threadIdx.x;
    if (idx < 65536) {                       // 2 layers * 2 sides * 128*128
        int l    = idx >> 15;
        int rem  = idx & 32767;
        int side = rem >> 14;
        int cw   = rem & 16383;
        int col  = cw >> 7, k = cw & 127;
        const float* W = side ? Wr : Wl;
        Wt[idx] = (_Float16)W[l * 16384 + k * 128 + col];
    } else if (idx < 65536 + 256) {
        int j = idx - 65536;
        atth[j] = (_Float16)att[j];
    }
}

// ---------------------------------------------------------------------------
// LDS-free MFMA GEMM, fp16 pipeline: wave = 32 rows x 256 cols.
// Layer 0: A from fp32 x via 1-op v_cvt_f16_f32; layer 1: A = fp16 h16.
// ---------------------------------------------------------------------------
__global__ __launch_bounds__(256) void gemm_mfma3(
        const _Float16* __restrict__ hA,          // fp16 N x 128 (layer 1) or null
        const float* __restrict__ Afp,            // fp32 N x 128 (layer 0) or null
        const _Float16* __restrict__ Wt,          // fp16 [2][128][128] this layer
        _Float16* __restrict__ xl, _Float16* __restrict__ xr, int n_rows) {
    const int wave = threadIdx.x >> 6;
    const int lane = threadIdx.x & 63;
    const int m = lane & 15;
    const int q = lane >> 4;
    const int r0 = (blockIdx.x * 4 + wave) * 32;

    int arow0 = r0 + m;        if (arow0 >= n_rows) arow0 = n_rows - 1;
    int arow1 = r0 + 16 + m;   if (arow1 >= n_rows) arow1 = n_rows - 1;

    floatx4 acc[2][2][8];      // [side][rt][ct]
#pragma unroll
    for (int s = 0; s < 2; ++s)
#pragma unroll
        for (int rt = 0; rt < 2; ++rt)
#pragma unroll
            for (int ct = 0; ct < 8; ++ct) acc[s][rt][ct] = (floatx4){0.f,0.f,0.f,0.f};

#pragma unroll
    for (int ks = 0; ks < 4; ++ks) {
        const int k0 = ks * 32 + q * 8;
        h8 a0, a1;
        if (Afp) {
            float4 f0 = *(const float4*)(Afp + (size_t)arow0 * 128 + k0);
            float4 f1 = *(const float4*)(Afp + (size_t)arow0 * 128 + k0 + 4);
            float4 g0 = *(const float4*)(Afp + (size_t)arow1 * 128 + k0);
            float4 g1 = *(const float4*)(Afp + (size_t)arow1 * 128 + k0 + 4);
            a0 = (h8){(_Float16)f0.x, (_Float16)f0.y, (_Float16)f0.z, (_Float16)f0.w,
                      (_Float16)f1.x, (_Float16)f1.y, (_Float16)f1.z, (_Float16)f1.w};
            a1 = (h8){(_Float16)g0.x, (_Float16)g0.y, (_Float16)g0.z, (_Float16)g0.w,
                      (_Float16)g1.x, (_Float16)g1.y, (_Float16)g1.z, (_Float16)g1.w};
        } else {
            a0 = *(const h8*)(hA + (size_t)arow0 * 128 + k0);
            a1 = *(const h8*)(hA + (size_t)arow1 * 128 + k0);
        }
#pragma unroll
        for (int s = 0; s < 2; ++s) {
#pragma unroll
            for (int ct = 0; ct < 8; ++ct) {
                h8 b = *(const h8*)(Wt + (size_t)s * 16384
                                    + (size_t)(ct * 16 + m) * 128 + k0);
                acc[s][0][ct] = __builtin_amdgcn_mfma_f32_16x16x32_f16(a0, b, acc[s][0][ct], 0, 0, 0);
                acc[s][1][ct] = __builtin_amdgcn_mfma_f32_16x16x32_f16(a1, b, acc[s][1][ct], 0, 0, 0);
            }
        }
    }

#pragma unroll
    for (int s = 0; s < 2; ++s) {
        _Float16* out = s ? xr : xl;
#pragma unroll
        for (int rt = 0; rt < 2; ++rt)
#pragma unroll
            for (int ct = 0; ct < 8; ++ct)
#pragma unroll
                for (int i = 0; i < 4; ++i) {
                    int row = r0 + rt * 16 + q * 4 + i;
                    if (row < n_rows)
                        out[(size_t)row * 128 + ct * 16 + m] = (_Float16)acc[s][rt][ct][i];
                }
    }
}

// ---------------------------------------------------------------------------
// Fused per-node GATv2, v10: v9's 3-slot pipeline + fp16 residual path.
//  - h_in comes from fp32 x (layer 0) or fp16 h16 (layer 1)  [-25.6 MB fetch]
//  - h_out goes to fp16 h16 (layer 0) or fp32 out (layer 1)  [-51.2 MB write]
// ---------------------------------------------------------------------------
union U16 { uint4 u; h2 h[4]; };

__global__ __launch_bounds__(256) void gat_node10(
        const _Float16* __restrict__ xl,          // fp16 N x 128
        const _Float16* __restrict__ xr,          // fp16 N x 128
        const float* __restrict__ h_in_f32,       // layer 0: x, else null
        const _Float16* __restrict__ h_in_f16,    // layer 1: h16, else null
        const int* __restrict__ rowstart, const int* __restrict__ csr_src,
        const _Float16* __restrict__ atth, const float* __restrict__ bias,
        const float* __restrict__ gamma, const float* __restrict__ beta,
        float* __restrict__ out_f32,              // layer 1 output, else null
        _Float16* __restrict__ out_f16) {         // layer 0 output, else null
    const int wave = threadIdx.x >> 6;
    const int lane = threadIdx.x & 63;
    const int node = blockIdx.x * 4 + wave;       // grid exact: 25000*4
    const int esub = lane >> 3;
    const int r    = lane & 7;
    const int c0   = r * 16;
    const int c    = c0 + 2 * esub;               // output channel pair

    const int p0 = rowstart[node], p1 = rowstart[node + 1];
    const int pe = p1 - 1;                        // deg >= 1 (self-loop)

    U16 xra, xrb, ata, atb;
    {
        const uint4* xp = (const uint4*)(xr + (size_t)node * 128 + c0);
        xra.u = xp[0]; xrb.u = xp[1];
        const uint4* ap = (const uint4*)(atth + c0);
        ata.u = ap[0]; atb.u = ap[1];
    }
    const float2 bi = *(const float2*)(bias + c); // epilogue const, hoisted
    const h2 ns2 = {(_Float16)NEG_SLOPE, (_Float16)NEG_SLOPE};

    const unsigned short* xls = (const unsigned short*)xl;

    float s = 0.f;
    h2 acc2[8];
#pragma unroll
    for (int j = 0; j < 8; ++j) acc2[j] = (h2){(_Float16)0.f, (_Float16)0.f};

    // dot + weighted accumulate for one 8-edge batch (two indep FMA chains)
    auto consume = [&](const U16& u0, const U16& u1, bool v) {
        float da = 0.f, db = 0.f;
#pragma unroll
        for (int qq = 0; qq < 4; ++qq) {
            h2 z  = u0.h[qq] + xra.h[qq];
            h2 lk = __builtin_elementwise_max(z, z * ns2);
            da = fdot2f(lk, ata.h[qq], da);
        }
#pragma unroll
        for (int qq = 0; qq < 4; ++qq) {
            h2 z  = u1.h[qq] + xrb.h[qq];
            h2 lk = __builtin_elementwise_max(z, z * ns2);
            db = fdot2f(lk, atb.h[qq], db);
        }
        float d = da + db;
        float alpha = d + __shfl_xor(d, 1);        // half-head pair -> head dot
        float w = v ? __expf(alpha) : 0.f;
        s += w;
        h2 w2 = {(_Float16)w, (_Float16)w};
#pragma unroll
        for (int qq = 0; qq < 4; ++qq)
            acc2[qq] = w2 * u0.h[qq] + acc2[qq];
#pragma unroll
        for (int qq = 0; qq < 4; ++qq)
            acc2[qq + 4] = w2 * u1.h[qq] + acc2[qq + 4];
    };

    // ---- prologue: indices for batches 0,1,2; gathers for batches 0,1 ----
    int pA = p0 + esub;        if (pA > pe) pA = pe;
    int pB = p0 + 8 + esub;    if (pB > pe) pB = pe;
    int pC = p0 + 16 + esub;   if (pC > pe) pC = pe;
    int i0 = csr_src[pA];
    int i1 = csr_src[pB];
    int i2 = csr_src[pC];

    U16 s0a, s0b, s1a, s1b, s2a, s2b;
    { const uint4* rp = (const uint4*)(xls + (size_t)i0 * 128 + c0); s0a.u = rp[0]; s0b.u = rp[1]; }
    { const uint4* rp = (const uint4*)(xls + (size_t)i1 * 128 + c0); s1a.u = rp[0]; s1b.u = rp[1]; }

    int pb = p0;
    for (;;) {
        // ---- body 0: csr t+3 -> i0; gather t+2 via i2 -> slot2; consume slot0
        {
            int pn = pb + 24 + esub; if (pn > pe) pn = pe;
            int inew = csr_src[pn];                         // batch t+3 index
            if (pb + 16 < p1) {                             // wave-uniform
                const uint4* rp = (const uint4*)(xls + (size_t)i2 * 128 + c0);
                s2a.u = rp[0]; s2b.u = rp[1];
            }
            consume(s0a, s0b, (pb + esub) < p1);
            i0 = inew;
            pb += 8; if (pb >= p1) break;
        }
        // ---- body 1: csr t+3 -> i1; gather t+2 via i0 -> slot0; consume slot1
        {
            int pn = pb + 24 + esub; if (pn > pe) pn = pe;
            int inew = csr_src[pn];
            if (pb + 16 < p1) {
                const uint4* rp = (const uint4*)(xls + (size_t)i0 * 128 + c0);
                s0a.u = rp[0]; s0b.u = rp[1];
            }
            consume(s1a, s1b, (pb + esub) < p1);
            i1 = inew;
            pb += 8; if (pb >= p1) break;
        }
        // ---- body 2: csr t+3 -> i2; gather t+2 via i1 -> slot1; consume slot2
        {
            int pn = pb + 24 + esub; if (pn > pe) pn = pe;
            int inew = csr_src[pn];
            if (pb + 16 < p1) {
                const uint4* rp = (const uint4*)(xls + (size_t)i1 * 128 + c0);
                s1a.u = rp[0]; s1b.u = rp[1];
            }
            consume(s2a, s2b, (pb + esub) < p1);
            i2 = inew;
            pb += 8; if (pb >= p1) break;
        }
    }

    // ---- per-head softmax denominator: sum s across esub lanes ----
    float ssum = s;
    ssum += __shfl_xor(ssum, 8);
    ssum += __shfl_xor(ssum, 16);
    ssum += __shfl_xor(ssum, 32);
    // every lane now holds S for head (r>>1) == head of its output channels

    // ---- cross-esub butterfly reduction of acc2 (recursive halving) ----
    const bool sel0 = (esub & 1) != 0;
    const bool sel1 = ((esub >> 1) & 1) != 0;
    const bool sel2 = ((esub >> 2) & 1) != 0;
    h2 b4[4];
#pragma unroll
    for (int k = 0; k < 4; ++k) {
        h2 keep = sel0 ? acc2[2 * k + 1] : acc2[2 * k];
        h2 send = sel0 ? acc2[2 * k]     : acc2[2 * k + 1];
        b4[k] = keep + shfl_xor_h2(send, 8);
    }
    h2 c2[2];
#pragma unroll
    for (int k = 0; k < 2; ++k) {
        h2 keep = sel1 ? b4[2 * k + 1] : b4[2 * k];
        h2 send = sel1 ? b4[2 * k]     : b4[2 * k + 1];
        c2[k] = keep + shfl_xor_h2(send, 16);
    }
    h2 keepf = sel2 ? c2[1] : c2[0];
    h2 sendf = sel2 ? c2[0] : c2[1];
    h2 tot = keepf + shfl_xor_h2(sendf, 32);
    // tot = channels (c, c+1) summed over all 8 edge slots

    const float invS = 1.f / ssum;
    float g0 = (float)tot[0] * invS + bi.x;
    float g1 = (float)tot[1] * invS + bi.y;

    // issue remaining epilogue loads before the LN allreduce (latency cover)
    const float2 ga = *(const float2*)(gamma + c);
    const float2 be = *(const float2*)(beta + c);
    float hx, hy;
    if (h_in_f16) {
        h2 hv = *(const h2*)(h_in_f16 + (size_t)node * 128 + c);
        hx = (float)hv[0]; hy = (float)hv[1];
    } else {
        float2 hv = *(const float2*)(h_in_f32 + (size_t)node * 128 + c);
        hx = hv.x; hy = hv.y;
    }

    // ---- LayerNorm over 128 channels (full-wave allreduce) ----
    float sum = g0 + g1, sq = g0 * g0 + g1 * g1;
#pragma unroll
    for (int off = 1; off < 64; off <<= 1) {
        sum += __shfl_xor(sum, off);
        sq  += __shfl_xor(sq, off);
    }
    float mu   = sum * (1.f / 128.f);
    float var  = sq * (1.f / 128.f) - mu * mu;
    float rstd = rsqrtf(var + LN_EPS);
    float y0 = (g0 - mu) * rstd * ga.x + be.x;
    float y1 = (g1 - mu) * rstd * ga.y + be.y;
    float e0 = (y0 > 0.f) ? y0 : (__expf(y0) - 1.f);
    float e1 = (y1 > 0.f) ? y1 : (__expf(y1) - 1.f);

    float ox = hx + e0;
    float oy = hy + e1;
    if (out_f32) {
        float2 o; o.x = ox; o.y = oy;
        *(float2*)(out_f32 + (size_t)node * 128 + c) = o;
    } else {
        h2 po = {(_Float16)ox, (_Float16)oy};
        *(h2*)(out_f16 + (size_t)node * 128 + c) = po;
    }
}

// ---------------------------------------------------------------------------
extern "C" void kernel_launch(void* const* d_in, const int* in_sizes, int n_in,
                              void* d_out, int out_size, void* d_ws, size_t ws_size,
                              hipStream_t stream) {
    const float* x     = (const float*)d_in[0];
    const int*   eidx  = (const int*)d_in[1];   // (2, E)
    const float* Wl    = (const float*)d_in[2]; // (L,128,128)
    const float* Wr    = (const float*)d_in[3];
    const float* att   = (const float*)d_in[4]; // (L,4,32) -> stride 128
    const float* bias  = (const float*)d_in[5];
    const float* gamma = (const float*)d_in[6];
    const float* beta  = (const float*)d_in[7];
    float* out = (float*)d_out;

    char* ws = (char*)d_ws;
    _Float16* xl = (_Float16*)ws;              ws += (size_t)N_NODES * 128 * 2;
    _Float16* xr = (_Float16*)ws;              ws += (size_t)N_NODES * 128 * 2;
    _Float16* h16 = (_Float16*)ws;             ws += (size_t)N_NODES * 128 * 2;
    _Float16* Wt  = (_Float16*)ws;             ws += (size_t)65536 * 2;
    _Float16* atth = (_Float16*)ws;            ws += 256 * 2;
    unsigned* pairbuf = (unsigned*)ws;         ws += (size_t)E2 * 4;
    int* tcnt     = (int*)ws; ws += (size_t)NTIL * NB * 4;
    int* toff     = (int*)ws; ws += (size_t)NTIL * NB * 4;
    int* bcnt     = (int*)ws; ws += (NB + 1) * 4;
    int* bstart   = (int*)ws; ws += (NB + 1) * 4;
    int* rowstart = (int*)ws; ws += (size_t)(N_NODES + 4) * 4;
    int* csr_src  = (int*)ws; ws += (size_t)E2 * 4;

    const int* edge_src = eidx;
    const int* edge_dst = eidx + E_EDGES;

    // ---- prep: weights -> transposed fp16, att -> fp16 ----
    prep_wt<<<257, 256, 0, stream>>>(Wl, Wr, att, Wt, atth);

    // ---- CSR build (no global atomics) ----
    tile_count<<<NTIL, 1024, 0, stream>>>(edge_dst, tcnt);
    col_scan<<<NB, 256, 0, stream>>>(tcnt, toff, bcnt);
    bucket_scan<<<1, 512, 0, stream>>>(bcnt, bstart, rowstart);
    tile_scatter<<<NTIL, 1024, 0, stream>>>(edge_src, edge_dst, bstart, toff, pairbuf);
    bucketize<<<NB, 1024, 0, stream>>>(pairbuf, bstart, rowstart, csr_src);

    // ---- two GATv2 layers (fp16 intermediate h16 between them) ----
    const int gemm_gx = (N_NODES + 127) / 128;   // 782
    for (int l = 0; l < 2; ++l) {
        gemm_mfma3<<<gemm_gx, 256, 0, stream>>>(
            (l == 0) ? nullptr : h16, (l == 0) ? x : nullptr,
            Wt + (size_t)l * 32768, xl, xr, N_NODES);
        gat_node10<<<N_NODES / 4, 256, 0, stream>>>(
            xl, xr,
            (l == 0) ? x : nullptr, (l == 0) ? nullptr : h16,
            rowstart, csr_src,
            atth + l * 128, bias + l * 128, gamma + l * 128, beta + l * 128,
            (l == 1) ? out : nullptr, (l == 0) ? h16 : nullptr);
    }
}